// Round 1
// baseline (935.015 us; speedup 1.0000x reference)
//
#include <hip/hip_runtime.h>
#include <stdint.h>

typedef __bf16   bf16x8 __attribute__((ext_vector_type(8)));
typedef float    f32x4  __attribute__((ext_vector_type(4)));
typedef uint16_t u16x8  __attribute__((ext_vector_type(8)));

using as1_cvp = const __attribute__((address_space(1))) void*;
using as3_vp  = __attribute__((address_space(3))) void*;

__device__ __forceinline__ uint16_t f2bf(float f) {
    uint32_t u = __float_as_uint(f);
    u += 0x7FFF + ((u >> 16) & 1);          // RNE
    return (uint16_t)(u >> 16);
}

__device__ __forceinline__ void gload16(const void* g, void* l) {
    __builtin_amdgcn_global_load_lds((as1_cvp)g, (as3_vp)l, 16, 0, 0);
}

#define MFMA16(a, b, c) __builtin_amdgcn_mfma_f32_16x16x32_bf16((a), (b), (c), 0, 0, 0)

// ---------------------------------------------------------------- f32 -> bf16
__global__ __launch_bounds__(256)
void cvt_bf16(const float* __restrict__ in, uint16_t* __restrict__ out, int n8)
{
    int i = blockIdx.x * 256 + threadIdx.x;
    if (i >= n8) return;
    const float4* p = reinterpret_cast<const float4*>(in) + (size_t)i * 2;
    float4 a = p[0], b = p[1];
    u16x8 o;
    o[0] = f2bf(a.x); o[1] = f2bf(a.y); o[2] = f2bf(a.z); o[3] = f2bf(a.w);
    o[4] = f2bf(b.x); o[5] = f2bf(b.y); o[6] = f2bf(b.z); o[7] = f2bf(b.w);
    reinterpret_cast<u16x8*>(out)[i] = o;
}

// ------------------------------------------------- C = A * B^T + bias (bf16 MFMA)
// A [M x K] bf16 row-major, Bt [N x K] bf16 row-major, C [M x N] bf16 or f32.
// 128x128 tile, BK=32, 4 waves (2x2), m97-structure.
template <int OUT_BF16>
__global__ __launch_bounds__(256)
void gemm_bt(const uint16_t* __restrict__ A, const uint16_t* __restrict__ Bt,
             const float* __restrict__ bias, void* __restrict__ Cout,
             int M, int N, int K)
{
    __shared__ uint16_t As[128 * 32];   // 8 KB
    __shared__ uint16_t Bs[128 * 32];   // 8 KB

    const int tid  = threadIdx.x;
    const int w    = tid >> 6;
    const int lane = tid & 63;
    const int g    = lane >> 4;
    const int l16  = lane & 15;
    const int wr   = w >> 1;
    const int wc   = w & 1;
    const int rb   = blockIdx.y * 128;
    const int cb   = blockIdx.x * 128;

    // staging: wave w owns 1KB chunks {2w, 2w+1} of each of As/Bs.
    // chunk c covers rows [c*16, c*16+16), lane L -> row c*16 + L/4, col (L&3)*8
    const int c0  = 2 * w, c1 = 2 * w + 1;
    const int sr0 = c0 * 16 + (lane >> 2);
    const int sr1 = c1 * 16 + (lane >> 2);
    const int sc  = (lane & 3) * 8;
    const uint16_t* gA0 = A  + (size_t)(rb + sr0) * K + sc;
    const uint16_t* gA1 = A  + (size_t)(rb + sr1) * K + sc;
    const uint16_t* gB0 = Bt + (size_t)(cb + sr0) * K + sc;
    const uint16_t* gB1 = Bt + (size_t)(cb + sr1) * K + sc;
    uint16_t* lA0 = &As[c0 * 512];
    uint16_t* lA1 = &As[c1 * 512];
    uint16_t* lB0 = &Bs[c0 * 512];
    uint16_t* lB1 = &Bs[c1 * 512];

    f32x4 acc[4][4] = {};

    for (int k0 = 0; k0 < K; k0 += 32) {
        __syncthreads();                      // LDS reuse guard
        gload16(gA0 + k0, lA0);
        gload16(gA1 + k0, lA1);
        gload16(gB0 + k0, lB0);
        gload16(gB1 + k0, lB1);
        __syncthreads();                      // staging complete (vmcnt drained)

        bf16x8 af[4], bfr[4];
#pragma unroll
        for (int m = 0; m < 4; ++m)
            af[m] = *reinterpret_cast<const bf16x8*>(&As[(wr * 64 + m * 16 + l16) * 32 + g * 8]);
#pragma unroll
        for (int n = 0; n < 4; ++n)
            bfr[n] = *reinterpret_cast<const bf16x8*>(&Bs[(wc * 64 + n * 16 + l16) * 32 + g * 8]);
#pragma unroll
        for (int m = 0; m < 4; ++m)
#pragma unroll
            for (int n = 0; n < 4; ++n)
                acc[m][n] = MFMA16(af[m], bfr[n], acc[m][n]);
    }

    float bv[4];
#pragma unroll
    for (int n = 0; n < 4; ++n) bv[n] = bias[cb + wc * 64 + n * 16 + l16];

#pragma unroll
    for (int m = 0; m < 4; ++m) {
#pragma unroll
        for (int n = 0; n < 4; ++n) {
            const int col = cb + wc * 64 + n * 16 + l16;
#pragma unroll
            for (int r = 0; r < 4; ++r) {
                const int row = rb + wr * 64 + m * 16 + g * 4 + r;
                float v = acc[m][n][r] + bv[n];
                if (OUT_BF16)
                    ((uint16_t*)Cout)[(size_t)row * N + col] = f2bf(v);
                else
                    ((float*)Cout)[(size_t)row * N + col] = v;
            }
        }
    }
}

// ------------------------------------------------------------------ attention
// One block per (bb, hh). 4 waves; wave w owns query rows [16w, 16w+16).
// Unscaled softmax(Q K^T) V, output scattered through the reference's
// cat/transpose/view permutation directly into Y (bf16 [4096 x 4096]).
__global__ __launch_bounds__(256)
void attn_kernel(const uint16_t* __restrict__ Q, const uint16_t* __restrict__ Kg,
                 const uint16_t* __restrict__ V, uint16_t* __restrict__ Y)
{
    const int bid = blockIdx.x;
    const int hh  = bid & 63;
    const int bb  = bid >> 6;
    const int tid = threadIdx.x;
    const int w   = tid >> 6, lane = tid & 63, g = lane >> 4, l16 = lane & 15;

    __shared__ uint16_t Vt[64 * 64];   // V transposed, XOR-swizzled (8 KB)
    __shared__ uint16_t Pl[64 * 64];   // P bf16, XOR-swizzled (8 KB)

    // ---- stage V transposed: Vt[l][k] = V[k][l], swizzle elem k ^= (l&7)<<3
    {
        const int k  = tid >> 2;
        const int l0 = (tid & 3) * 16;
        const uint16_t* src = V + (size_t)(bb * 64 + k) * 4096 + hh * 64 + l0;
        u16x8 v0 = *reinterpret_cast<const u16x8*>(src);
        u16x8 v1 = *reinterpret_cast<const u16x8*>(src + 8);
#pragma unroll
        for (int i = 0; i < 8; ++i) {
            int l = l0 + i;
            Vt[l * 64 + (k ^ ((l & 7) << 3))] = v0[i];
        }
#pragma unroll
        for (int i = 0; i < 8; ++i) {
            int l = l0 + 8 + i;
            Vt[l * 64 + (k ^ ((l & 7) << 3))] = v1[i];
        }
    }

    // ---- S = Q K^T (rows 16w..16w+16, all 64 cols), direct-global fragments
    f32x4 sa[4] = {};
    {
        const uint16_t* qrow = Q + (size_t)(bb * 64 + w * 16 + l16) * 4096 + hh * 64 + g * 8;
        bf16x8 a0 = *reinterpret_cast<const bf16x8*>(qrow);
        bf16x8 a1 = *reinterpret_cast<const bf16x8*>(qrow + 32);
#pragma unroll
        for (int n = 0; n < 4; ++n) {
            const uint16_t* krow = Kg + (size_t)(bb * 64 + n * 16 + l16) * 4096 + hh * 64 + g * 8;
            bf16x8 b0 = *reinterpret_cast<const bf16x8*>(krow);
            bf16x8 b1 = *reinterpret_cast<const bf16x8*>(krow + 32);
            sa[n] = MFMA16(a0, b0, sa[n]);
            sa[n] = MFMA16(a1, b1, sa[n]);
        }
    }

    // ---- softmax (no 1/sqrt(hd) scale, faithful). Row q = 16w + 4g + j;
    // its 64 values live as regs n=0..3 across the 16-lane group (l16).
    float p[4][4];
#pragma unroll
    for (int j = 0; j < 4; ++j) {
        float mx = fmaxf(fmaxf(sa[0][j], sa[1][j]), fmaxf(sa[2][j], sa[3][j]));
        mx = fmaxf(mx, __shfl_xor(mx, 1));
        mx = fmaxf(mx, __shfl_xor(mx, 2));
        mx = fmaxf(mx, __shfl_xor(mx, 4));
        mx = fmaxf(mx, __shfl_xor(mx, 8));
        float s = 0.f;
#pragma unroll
        for (int n = 0; n < 4; ++n) { p[n][j] = __expf(sa[n][j] - mx); s += p[n][j]; }
        s += __shfl_xor(s, 1);
        s += __shfl_xor(s, 2);
        s += __shfl_xor(s, 4);
        s += __shfl_xor(s, 8);
        float inv = 1.0f / s;
#pragma unroll
        for (int n = 0; n < 4; ++n) p[n][j] *= inv;
    }

    // ---- P -> LDS in A-operand-friendly layout (swizzled)
#pragma unroll
    for (int j = 0; j < 4; ++j) {
        const int q = w * 16 + g * 4 + j;
#pragma unroll
        for (int n = 0; n < 4; ++n) {
            const int kcol = n * 16 + l16;
            Pl[q * 64 + (kcol ^ ((q & 7) << 3))] = f2bf(p[n][j]);
        }
    }
    __syncthreads();   // Vt (all threads) + Pl ready

    // ---- O = P V
    f32x4 oa[4] = {};
    {
        const int qr = w * 16 + l16;
        bf16x8 a0 = *reinterpret_cast<const bf16x8*>(&Pl[qr * 64 + ((g * 8)      ^ ((qr & 7) << 3))]);
        bf16x8 a1 = *reinterpret_cast<const bf16x8*>(&Pl[qr * 64 + ((32 + g * 8) ^ ((qr & 7) << 3))]);
#pragma unroll
        for (int n = 0; n < 4; ++n) {
            const int vr = n * 16 + l16;
            bf16x8 b0 = *reinterpret_cast<const bf16x8*>(&Vt[vr * 64 + ((g * 8)      ^ ((vr & 7) << 3))]);
            bf16x8 b1 = *reinterpret_cast<const bf16x8*>(&Vt[vr * 64 + ((32 + g * 8) ^ ((vr & 7) << 3))]);
            oa[n] = MFMA16(a0, b0, oa[n]);
            oa[n] = MFMA16(a1, b1, oa[n]);
        }
    }

    // ---- permuted store: Ostd[bb,hh,qq,ll] -> Y[b, s, h*64 + l]
#pragma unroll
    for (int n = 0; n < 4; ++n) {
        const int ll = n * 16 + l16;
#pragma unroll
        for (int r = 0; r < 4; ++r) {
            const int qq = w * 16 + g * 4 + r;
            const int b_ = (bb >> 1) + ((ll >= 32) ? 32 : 0);
            const int s_ = ((bb & 1) << 5) + (qq >> 1);
            const int h_ = ((qq & 1) << 5) + (hh >> 1);
            const int l_ = ((hh & 1) << 5) + (ll & 31);
            Y[(size_t)(b_ * 64 + s_) * 4096 + h_ * 64 + l_] = f2bf(oa[n][r]);
        }
    }
}

// ----------------------------------------------------------------------------
extern "C" void kernel_launch(void* const* d_in, const int* in_sizes, int n_in,
                              void* d_out, int out_size, void* d_ws, size_t ws_size,
                              hipStream_t stream)
{
    (void)in_sizes; (void)n_in; (void)out_size; (void)ws_size;

    const float* x  = (const float*)d_in[0];
    const float* Wq = (const float*)d_in[1];
    const float* bq = (const float*)d_in[2];
    const float* Wk = (const float*)d_in[3];
    const float* bk = (const float*)d_in[4];
    const float* Wv = (const float*)d_in[5];
    const float* bv = (const float*)d_in[6];
    const float* Wp = (const float*)d_in[7];
    const float* bp = (const float*)d_in[8];
    float* out = (float*)d_out;

    const size_t NN = 16777216;            // 4096*4096 elements
    uint16_t* xb   = (uint16_t*)d_ws;      // 32 MB, later reused as Y
    uint16_t* wb   = xb + NN;              // 32 MB (sequential weight buffer)
    uint16_t* Qb   = wb + NN;              // 32 MB
    uint16_t* Kb   = Qb + NN;              // 32 MB
    uint16_t* Vb   = Kb + NN;              // 32 MB   (total 160 MB)
    uint16_t* Yb   = xb;

    const int n8 = (int)(NN / 8);
    dim3 cgrid((n8 + 255) / 256), cblk(256);
    dim3 ggrid(32, 32), gblk(256);

    cvt_bf16<<<cgrid, cblk, 0, stream>>>(x, xb, n8);

    cvt_bf16<<<cgrid, cblk, 0, stream>>>(Wq, wb, n8);
    gemm_bt<1><<<ggrid, gblk, 0, stream>>>(xb, wb, bq, (void*)Qb, 4096, 4096, 4096);

    cvt_bf16<<<cgrid, cblk, 0, stream>>>(Wk, wb, n8);
    gemm_bt<1><<<ggrid, gblk, 0, stream>>>(xb, wb, bk, (void*)Kb, 4096, 4096, 4096);

    cvt_bf16<<<cgrid, cblk, 0, stream>>>(Wv, wb, n8);
    gemm_bt<1><<<ggrid, gblk, 0, stream>>>(xb, wb, bv, (void*)Vb, 4096, 4096, 4096);

    attn_kernel<<<dim3(4096), dim3(256), 0, stream>>>(Qb, Kb, Vb, Yb);

    cvt_bf16<<<cgrid, cblk, 0, stream>>>(Wp, wb, n8);
    gemm_bt<0><<<ggrid, gblk, 0, stream>>>(Yb, wb, bp, (void*)out, 4096, 4096, 4096);
}

// Round 3
// 685.371 us; speedup vs baseline: 1.3642x; 1.3642x over previous
//
#include <hip/hip_runtime.h>
#include <stdint.h>

typedef __bf16   bf16x8 __attribute__((ext_vector_type(8)));
typedef float    f32x4  __attribute__((ext_vector_type(4)));
typedef uint16_t u16x8  __attribute__((ext_vector_type(8)));

using as1_cvp = const __attribute__((address_space(1))) void*;
using as3_vp  = __attribute__((address_space(3))) void*;

__device__ __forceinline__ uint16_t f2bf(float f) {
    uint32_t u = __float_as_uint(f);
    u += 0x7FFF + ((u >> 16) & 1);          // RNE
    return (uint16_t)(u >> 16);
}

__device__ __forceinline__ void gload16(const void* g, void* l) {
    __builtin_amdgcn_global_load_lds((as1_cvp)g, (as3_vp)l, 16, 0, 0);
}

#define MFMA16(a, b, c) __builtin_amdgcn_mfma_f32_16x16x32_bf16((a), (b), (c), 0, 0, 0)

// ---------------------------------------------------------------- f32 -> bf16
__global__ __launch_bounds__(256)
void cvt_bf16(const float* __restrict__ in, uint16_t* __restrict__ out, int n8)
{
    int i = blockIdx.x * 256 + threadIdx.x;
    if (i >= n8) return;
    const float4* p = reinterpret_cast<const float4*>(in) + (size_t)i * 2;
    float4 a = p[0], b = p[1];
    u16x8 o;
    o[0] = f2bf(a.x); o[1] = f2bf(a.y); o[2] = f2bf(a.z); o[3] = f2bf(a.w);
    o[4] = f2bf(b.x); o[5] = f2bf(b.y); o[6] = f2bf(b.z); o[7] = f2bf(b.w);
    reinterpret_cast<u16x8*>(out)[i] = o;
}

// ---------------------------------------------------------------------------
// 256x256 8-phase GEMM: C = A * Bt^T + bias. A [M x K], Bt [N x K] bf16
// row-major. 8 waves (2M x 4N), BK=64 as 2 K-halves of 32. LDS 128 KiB
// double-buffered, XOR-swizzled (16B block ^= row&3, 2-bit — block index has
// only 4 values per 32-elem K-half row) via pre-swizzled global sources
// (linear gload_lds dest, rule 21). Counted vmcnt(4) once per K-tile.
// Per-wave output 128x64 = acc[8][4] f32x4.
// ---------------------------------------------------------------------------
template <int OUT_BF16>
__global__ __launch_bounds__(512, 2)
void gemm256(const uint16_t* __restrict__ A, const uint16_t* __restrict__ Bt,
             const float* __restrict__ bias, void* __restrict__ Cout,
             int M, int N, int K)
{
    __shared__ uint16_t lds[65536];        // [buf][kh] x (A 256x32 | B 256x32)
    const int NT = K >> 6;                 // K-tiles of 64

    int bid = blockIdx.x;
    bid = (bid & 7) * 32 + (bid >> 3);     // XCD-aware swizzle (nwg=256, %8==0)
    const int bx = bid & 15, by = bid >> 4;
    const int rb = by * 256, cb = bx * 256;

    const int tid  = threadIdx.x;
    const int w    = tid >> 6;
    const int lane = tid & 63;
    const int g    = lane >> 4;
    const int l16  = lane & 15;
    const int wm   = w >> 2;               // 0..1
    const int wn   = w & 3;                // 0..3
    const int srow = lane >> 2;            // stage: 4 lanes per 64B row
    const int sblk = lane & 3;             // stage: 16B block within row

    f32x4 acc[8][4] = {};

    // stage one 16KB unit (256 rows x 32 k) of A or B, k-half kh, into buf.
    auto stageA = [&](int buf, int kh, int kbase) {
#pragma unroll
        for (int i = 0; i < 2; ++i) {
            const int row = i * 128 + w * 16 + srow;
            const uint16_t* src = A + (size_t)(rb + row) * K + kbase
                                    + ((sblk ^ (row & 3)) << 3);
            gload16(src, &lds[(buf * 2 + kh) * 16384 + i * 4096 + w * 512]);
        }
    };
    auto stageB = [&](int buf, int kh, int kbase) {
#pragma unroll
        for (int i = 0; i < 2; ++i) {
            const int row = i * 128 + w * 16 + srow;
            const uint16_t* src = Bt + (size_t)(cb + row) * K + kbase
                                     + ((sblk ^ (row & 3)) << 3);
            gload16(src, &lds[(buf * 2 + kh) * 16384 + 8192 + i * 4096 + w * 512]);
        }
    };

    // ---- prologue: tile 0 complete + tile 1 k-half 0 (12 loads in flight)
    stageA(0, 0, 0);  stageB(0, 0, 0);
    stageA(0, 1, 32); stageB(0, 1, 32);
    stageA(1, 0, 64); stageB(1, 0, 64);
    asm volatile("s_waitcnt vmcnt(4)" ::: "memory");   // tile 0 landed
    __builtin_amdgcn_s_barrier();

    // ---- main loop: 4 phases per K-tile.
    // stage schedule: ph0: Ak1(t+1)  ph1: Bk1(t+1)  ph2: Ak0(t+2)  ph3: Bk0(t+2)
    // every unit staged >=5 phases before first read; vmcnt(4) at each tile
    // boundary guarantees all but the last 2 units landed.
    for (int t = 0; t < NT; ++t) {
        const int cur = t & 1, nxt = cur ^ 1;
#pragma unroll
        for (int ph = 0; ph < 4; ++ph) {
            const int kh  = ph >> 1;       // k-half read this phase
            const int grp = ph & 1;        // m-frag group read this phase
            const int base = (cur * 2 + kh) * 16384;

            bf16x8 af[4], bfr[4];
#pragma unroll
            for (int mi = 0; mi < 4; ++mi) {
                const int r = wm * 128 + grp * 64 + mi * 16 + l16;
                af[mi] = *reinterpret_cast<const bf16x8*>(
                    &lds[base + r * 32 + ((g ^ (r & 3)) << 3)]);
            }
#pragma unroll
            for (int n = 0; n < 4; ++n) {
                const int c = wn * 64 + n * 16 + l16;
                bfr[n] = *reinterpret_cast<const bf16x8*>(
                    &lds[base + 8192 + c * 32 + ((g ^ (c & 3)) << 3)]);
            }

            if (ph == 0 && t + 1 < NT) stageA(nxt, 1, (t + 1) * 64 + 32);
            if (ph == 1 && t + 1 < NT) stageB(nxt, 1, (t + 1) * 64 + 32);
            if (ph == 2 && t + 2 < NT) stageA(cur, 0, (t + 2) * 64);
            if (ph == 3 && t + 2 < NT) stageB(cur, 0, (t + 2) * 64);

            __builtin_amdgcn_s_barrier();
            asm volatile("s_waitcnt lgkmcnt(0)" ::: "memory");
            __builtin_amdgcn_sched_barrier(0);
            __builtin_amdgcn_s_setprio(1);
#pragma unroll
            for (int mi = 0; mi < 4; ++mi)
#pragma unroll
                for (int n = 0; n < 4; ++n)
                    acc[grp * 4 + mi][n] = MFMA16(af[mi], bfr[n], acc[grp * 4 + mi][n]);
            __builtin_amdgcn_s_setprio(0);
            if (ph == 3) {
                if (t >= NT - 2) asm volatile("s_waitcnt vmcnt(0)" ::: "memory");
                else             asm volatile("s_waitcnt vmcnt(4)" ::: "memory");
            }
            __builtin_amdgcn_s_barrier();
        }
    }

    // ---- epilogue
    float bv[4];
#pragma unroll
    for (int n = 0; n < 4; ++n) bv[n] = bias[cb + wn * 64 + n * 16 + l16];

#pragma unroll
    for (int m = 0; m < 8; ++m) {
#pragma unroll
        for (int n = 0; n < 4; ++n) {
            const int col = cb + wn * 64 + n * 16 + l16;
#pragma unroll
            for (int r = 0; r < 4; ++r) {
                const int row = rb + wm * 128 + m * 16 + g * 4 + r;
                float v = acc[m][n][r] + bv[n];
                if (OUT_BF16)
                    ((uint16_t*)Cout)[(size_t)row * N + col] = f2bf(v);
                else
                    ((float*)Cout)[(size_t)row * N + col] = v;
            }
        }
    }
}

// ------------------------------------------------------------------ attention
// One block per (bb, hh). 4 waves; wave w owns query rows [16w, 16w+16).
// Unscaled softmax(Q K^T) V, output scattered through the reference's
// cat/transpose/view permutation directly into Y (bf16 [4096 x 4096]).
__global__ __launch_bounds__(256)
void attn_kernel(const uint16_t* __restrict__ Q, const uint16_t* __restrict__ Kg,
                 const uint16_t* __restrict__ V, uint16_t* __restrict__ Y)
{
    const int bid = blockIdx.x;
    const int hh  = bid & 63;
    const int bb  = bid >> 6;
    const int tid = threadIdx.x;
    const int w   = tid >> 6, lane = tid & 63, g = lane >> 4, l16 = lane & 15;

    __shared__ uint16_t Vt[64 * 64];   // V transposed, XOR-swizzled (8 KB)
    __shared__ uint16_t Pl[64 * 64];   // P bf16, XOR-swizzled (8 KB)

    // ---- stage V transposed: Vt[l][k] = V[k][l], swizzle elem k ^= (l&7)<<3
    {
        const int k  = tid >> 2;
        const int l0 = (tid & 3) * 16;
        const uint16_t* src = V + (size_t)(bb * 64 + k) * 4096 + hh * 64 + l0;
        u16x8 v0 = *reinterpret_cast<const u16x8*>(src);
        u16x8 v1 = *reinterpret_cast<const u16x8*>(src + 8);
#pragma unroll
        for (int i = 0; i < 8; ++i) {
            int l = l0 + i;
            Vt[l * 64 + (k ^ ((l & 7) << 3))] = v0[i];
        }
#pragma unroll
        for (int i = 0; i < 8; ++i) {
            int l = l0 + 8 + i;
            Vt[l * 64 + (k ^ ((l & 7) << 3))] = v1[i];
        }
    }

    // ---- S = Q K^T (rows 16w..16w+16, all 64 cols), direct-global fragments
    f32x4 sa[4] = {};
    {
        const uint16_t* qrow = Q + (size_t)(bb * 64 + w * 16 + l16) * 4096 + hh * 64 + g * 8;
        bf16x8 a0 = *reinterpret_cast<const bf16x8*>(qrow);
        bf16x8 a1 = *reinterpret_cast<const bf16x8*>(qrow + 32);
#pragma unroll
        for (int n = 0; n < 4; ++n) {
            const uint16_t* krow = Kg + (size_t)(bb * 64 + n * 16 + l16) * 4096 + hh * 64 + g * 8;
            bf16x8 b0 = *reinterpret_cast<const bf16x8*>(krow);
            bf16x8 b1 = *reinterpret_cast<const bf16x8*>(krow + 32);
            sa[n] = MFMA16(a0, b0, sa[n]);
            sa[n] = MFMA16(a1, b1, sa[n]);
        }
    }

    // ---- softmax (no 1/sqrt(hd) scale, faithful). Row q = 16w + 4g + j;
    // its 64 values live as regs n=0..3 across the 16-lane group (l16).
    float p[4][4];
#pragma unroll
    for (int j = 0; j < 4; ++j) {
        float mx = fmaxf(fmaxf(sa[0][j], sa[1][j]), fmaxf(sa[2][j], sa[3][j]));
        mx = fmaxf(mx, __shfl_xor(mx, 1));
        mx = fmaxf(mx, __shfl_xor(mx, 2));
        mx = fmaxf(mx, __shfl_xor(mx, 4));
        mx = fmaxf(mx, __shfl_xor(mx, 8));
        float s = 0.f;
#pragma unroll
        for (int n = 0; n < 4; ++n) { p[n][j] = __expf(sa[n][j] - mx); s += p[n][j]; }
        s += __shfl_xor(s, 1);
        s += __shfl_xor(s, 2);
        s += __shfl_xor(s, 4);
        s += __shfl_xor(s, 8);
        float inv = 1.0f / s;
#pragma unroll
        for (int n = 0; n < 4; ++n) p[n][j] *= inv;
    }

    // ---- P -> LDS in A-operand-friendly layout (swizzled)
#pragma unroll
    for (int j = 0; j < 4; ++j) {
        const int q = w * 16 + g * 4 + j;
#pragma unroll
        for (int n = 0; n < 4; ++n) {
            const int kcol = n * 16 + l16;
            Pl[q * 64 + (kcol ^ ((q & 7) << 3))] = f2bf(p[n][j]);
        }
    }
    __syncthreads();   // Vt (all threads) + Pl ready

    // ---- O = P V
    f32x4 oa[4] = {};
    {
        const int qr = w * 16 + l16;
        bf16x8 a0 = *reinterpret_cast<const bf16x8*>(&Pl[qr * 64 + ((g * 8)      ^ ((qr & 7) << 3))]);
        bf16x8 a1 = *reinterpret_cast<const bf16x8*>(&Pl[qr * 64 + ((32 + g * 8) ^ ((qr & 7) << 3))]);
#pragma unroll
        for (int n = 0; n < 4; ++n) {
            const int vr = n * 16 + l16;
            bf16x8 b0 = *reinterpret_cast<const bf16x8*>(&Vt[vr * 64 + ((g * 8)      ^ ((vr & 7) << 3))]);
            bf16x8 b1 = *reinterpret_cast<const bf16x8*>(&Vt[vr * 64 + ((32 + g * 8) ^ ((vr & 7) << 3))]);
            oa[n] = MFMA16(a0, b0, oa[n]);
            oa[n] = MFMA16(a1, b1, oa[n]);
        }
    }

    // ---- permuted store: Ostd[bb,hh,qq,ll] -> Y[b, s, h*64 + l]
#pragma unroll
    for (int n = 0; n < 4; ++n) {
        const int ll = n * 16 + l16;
#pragma unroll
        for (int r = 0; r < 4; ++r) {
            const int qq = w * 16 + g * 4 + r;
            const int b_ = (bb >> 1) + ((ll >= 32) ? 32 : 0);
            const int s_ = ((bb & 1) << 5) + (qq >> 1);
            const int h_ = ((qq & 1) << 5) + (hh >> 1);
            const int l_ = ((hh & 1) << 5) + (ll & 31);
            Y[(size_t)(b_ * 64 + s_) * 4096 + h_ * 64 + l_] = f2bf(oa[n][r]);
        }
    }
}

// ----------------------------------------------------------------------------
extern "C" void kernel_launch(void* const* d_in, const int* in_sizes, int n_in,
                              void* d_out, int out_size, void* d_ws, size_t ws_size,
                              hipStream_t stream)
{
    (void)in_sizes; (void)n_in; (void)out_size; (void)ws_size;

    const float* x  = (const float*)d_in[0];
    const float* Wq = (const float*)d_in[1];
    const float* bq = (const float*)d_in[2];
    const float* Wk = (const float*)d_in[3];
    const float* bk = (const float*)d_in[4];
    const float* Wv = (const float*)d_in[5];
    const float* bv = (const float*)d_in[6];
    const float* Wp = (const float*)d_in[7];
    const float* bp = (const float*)d_in[8];
    float* out = (float*)d_out;

    const size_t NN = 16777216;            // 4096*4096 elements
    uint16_t* xb   = (uint16_t*)d_ws;      // 32 MB, later reused as Y
    uint16_t* wb   = xb + NN;              // 32 MB (sequential weight buffer)
    uint16_t* Qb   = wb + NN;              // 32 MB
    uint16_t* Kb   = Qb + NN;              // 32 MB
    uint16_t* Vb   = Kb + NN;              // 32 MB   (total 160 MB)
    uint16_t* Yb   = xb;

    const int n8 = (int)(NN / 8);
    dim3 cgrid((n8 + 255) / 256), cblk(256);
    dim3 ggrid(256), gblk(512);

    cvt_bf16<<<cgrid, cblk, 0, stream>>>(x, xb, n8);

    cvt_bf16<<<cgrid, cblk, 0, stream>>>(Wq, wb, n8);
    gemm256<1><<<ggrid, gblk, 0, stream>>>(xb, wb, bq, (void*)Qb, 4096, 4096, 4096);

    cvt_bf16<<<cgrid, cblk, 0, stream>>>(Wk, wb, n8);
    gemm256<1><<<ggrid, gblk, 0, stream>>>(xb, wb, bk, (void*)Kb, 4096, 4096, 4096);

    cvt_bf16<<<cgrid, cblk, 0, stream>>>(Wv, wb, n8);
    gemm256<1><<<ggrid, gblk, 0, stream>>>(xb, wb, bv, (void*)Vb, 4096, 4096, 4096);

    attn_kernel<<<dim3(4096), dim3(256), 0, stream>>>(Qb, Kb, Vb, Yb);

    cvt_bf16<<<cgrid, cblk, 0, stream>>>(Wp, wb, n8);
    gemm256<0><<<ggrid, gblk, 0, stream>>>(Yb, wb, bp, (void*)out, 4096, 4096, 4096);
}

// Round 4
// 627.924 us; speedup vs baseline: 1.4891x; 1.0915x over previous
//
#include <hip/hip_runtime.h>
#include <stdint.h>

typedef __bf16   bf16x8 __attribute__((ext_vector_type(8)));
typedef float    f32x4  __attribute__((ext_vector_type(4)));
typedef uint16_t u16x8  __attribute__((ext_vector_type(8)));

using as1_cvp = const __attribute__((address_space(1))) void*;
using as3_vp  = __attribute__((address_space(3))) void*;

__device__ __forceinline__ uint16_t f2bf(float f) {
    uint32_t u = __float_as_uint(f);
    u += 0x7FFF + ((u >> 16) & 1);          // RNE
    return (uint16_t)(u >> 16);
}

__device__ __forceinline__ void gload16(const void* g, void* l) {
    __builtin_amdgcn_global_load_lds((as1_cvp)g, (as3_vp)l, 16, 0, 0);
}

#define MFMA16(a, b, c) __builtin_amdgcn_mfma_f32_16x16x32_bf16((a), (b), (c), 0, 0, 0)

// ---------------------------------------------------------------- f32 -> bf16
__global__ __launch_bounds__(256)
void cvt_bf16(const float* __restrict__ in, uint16_t* __restrict__ out, int n8)
{
    int i = blockIdx.x * 256 + threadIdx.x;
    if (i >= n8) return;
    const float4* p = reinterpret_cast<const float4*>(in) + (size_t)i * 2;
    float4 a = p[0], b = p[1];
    u16x8 o;
    o[0] = f2bf(a.x); o[1] = f2bf(a.y); o[2] = f2bf(a.z); o[3] = f2bf(a.w);
    o[4] = f2bf(b.x); o[5] = f2bf(b.y); o[6] = f2bf(b.z); o[7] = f2bf(b.w);
    reinterpret_cast<u16x8*>(out)[i] = o;
}

// ---------------------------------------------------------------------------
// 256x256 8-phase GEMM: C = A * Bt^T + bias. A [M x K], Bt [N x K] bf16
// row-major. 8 waves (2M x 4N), BK=64 as 2 K-halves of 32 (64B LDS rows).
// LDS 128 KiB double-buffered. Swizzle: 16B block ^= (row>>1)&3 — for 64B
// rows bank = 16*(r&1) + 4*blk, so the XOR field must be (r>>1)&3 to give
// each bank exactly 2 accesses per 16-lane group (round-3 fix: r&3 left
// even/odd lanes 4-deep on half the quads -> +4 cyc/read).
// B-fragments read once per K-tile (grp=0 phase) and held in registers
// across the barrier for the grp=1 phase: 24 instead of 32 reads/wave/tile.
// Counted vmcnt(4) once per K-tile. Per-wave output 128x64 = acc[8][4].
// ---------------------------------------------------------------------------
template <int OUT_BF16>
__global__ __launch_bounds__(512, 2)
void gemm256(const uint16_t* __restrict__ A, const uint16_t* __restrict__ Bt,
             const float* __restrict__ bias, void* __restrict__ Cout,
             int M, int N, int K)
{
    __shared__ uint16_t lds[65536];        // [buf][kh] x (A 256x32 | B 256x32)
    const int NT = K >> 6;                 // K-tiles of 64

    int bid = blockIdx.x;
    bid = (bid & 7) * 32 + (bid >> 3);     // XCD-aware swizzle (nwg=256, %8==0)
    const int bx = bid & 15, by = bid >> 4;
    const int rb = by * 256, cb = bx * 256;

    const int tid  = threadIdx.x;
    const int w    = tid >> 6;
    const int lane = tid & 63;
    const int g    = lane >> 4;
    const int l16  = lane & 15;
    const int wm   = w >> 2;               // 0..1
    const int wn   = w & 3;                // 0..3
    const int srow = lane >> 2;            // stage: 4 lanes per 64B row
    const int sblk = lane & 3;             // stage: 16B block within row

    f32x4 acc[8][4] = {};

    // stage one 16KB unit (256 rows x 32 k) of A or B, k-half kh, into buf.
    auto stageA = [&](int buf, int kh, int kbase) {
#pragma unroll
        for (int i = 0; i < 2; ++i) {
            const int row = i * 128 + w * 16 + srow;
            const uint16_t* src = A + (size_t)(rb + row) * K + kbase
                                    + ((sblk ^ ((row >> 1) & 3)) << 3);
            gload16(src, &lds[(buf * 2 + kh) * 16384 + i * 4096 + w * 512]);
        }
    };
    auto stageB = [&](int buf, int kh, int kbase) {
#pragma unroll
        for (int i = 0; i < 2; ++i) {
            const int row = i * 128 + w * 16 + srow;
            const uint16_t* src = Bt + (size_t)(cb + row) * K + kbase
                                     + ((sblk ^ ((row >> 1) & 3)) << 3);
            gload16(src, &lds[(buf * 2 + kh) * 16384 + 8192 + i * 4096 + w * 512]);
        }
    };

    // ---- prologue: tile 0 complete + tile 1 k-half 0 (12 loads in flight)
    stageA(0, 0, 0);  stageB(0, 0, 0);
    stageA(0, 1, 32); stageB(0, 1, 32);
    stageA(1, 0, 64); stageB(1, 0, 64);
    asm volatile("s_waitcnt vmcnt(4)" ::: "memory");   // tile 0 landed
    __builtin_amdgcn_s_barrier();

    // ---- main loop: 4 phases per K-tile, (kh,grp) = (0,0),(0,1),(1,0),(1,1).
    // stage schedule: ph0: Ak1(t+1)  ph1: Bk1(t+1)  ph2: Ak0(t+2)  ph3: Bk0(t+2)
    // every unit staged >=5 phases before first read; vmcnt(4) at each tile
    // boundary guarantees all but the last 2 units landed.
    for (int t = 0; t < NT; ++t) {
        const int cur = t & 1, nxt = cur ^ 1;
        bf16x8 bfr[4];
#pragma unroll
        for (int ph = 0; ph < 4; ++ph) {
            const int kh  = ph >> 1;       // k-half read this phase
            const int grp = ph & 1;        // m-frag group read this phase
            const int base = (cur * 2 + kh) * 16384;

            bf16x8 af[4];
#pragma unroll
            for (int mi = 0; mi < 4; ++mi) {
                const int r = wm * 128 + grp * 64 + mi * 16 + l16;
                af[mi] = *reinterpret_cast<const bf16x8*>(
                    &lds[base + r * 32 + ((g ^ ((r >> 1) & 3)) << 3)]);
            }
            if (grp == 0) {                // B frags once per (tile, kh)
#pragma unroll
                for (int n = 0; n < 4; ++n) {
                    const int c = wn * 64 + n * 16 + l16;
                    bfr[n] = *reinterpret_cast<const bf16x8*>(
                        &lds[base + 8192 + c * 32 + ((g ^ ((c >> 1) & 3)) << 3)]);
                }
            }

            if (ph == 0 && t + 1 < NT) stageA(nxt, 1, (t + 1) * 64 + 32);
            if (ph == 1 && t + 1 < NT) stageB(nxt, 1, (t + 1) * 64 + 32);
            if (ph == 2 && t + 2 < NT) stageA(cur, 0, (t + 2) * 64);
            if (ph == 3 && t + 2 < NT) stageB(cur, 0, (t + 2) * 64);

            __builtin_amdgcn_s_barrier();
            asm volatile("s_waitcnt lgkmcnt(0)" ::: "memory");
            __builtin_amdgcn_sched_barrier(0);
            __builtin_amdgcn_s_setprio(1);
#pragma unroll
            for (int mi = 0; mi < 4; ++mi)
#pragma unroll
                for (int n = 0; n < 4; ++n)
                    acc[grp * 4 + mi][n] = MFMA16(af[mi], bfr[n], acc[grp * 4 + mi][n]);
            __builtin_amdgcn_s_setprio(0);
            if (ph == 3) {
                if (t >= NT - 2) asm volatile("s_waitcnt vmcnt(0)" ::: "memory");
                else             asm volatile("s_waitcnt vmcnt(4)" ::: "memory");
            }
            __builtin_amdgcn_s_barrier();
        }
    }

    // ---- epilogue
    float bv[4];
#pragma unroll
    for (int n = 0; n < 4; ++n) bv[n] = bias[cb + wn * 64 + n * 16 + l16];

#pragma unroll
    for (int m = 0; m < 8; ++m) {
#pragma unroll
        for (int n = 0; n < 4; ++n) {
            const int col = cb + wn * 64 + n * 16 + l16;
#pragma unroll
            for (int r = 0; r < 4; ++r) {
                const int row = rb + wm * 128 + m * 16 + g * 4 + r;
                float v = acc[m][n][r] + bv[n];
                if (OUT_BF16)
                    ((uint16_t*)Cout)[(size_t)row * N + col] = f2bf(v);
                else
                    ((float*)Cout)[(size_t)row * N + col] = v;
            }
        }
    }
}

// ------------------------------------------------------------------ attention
// One block per (bb, hh). 4 waves; wave w owns query rows [16w, 16w+16).
// Unscaled softmax(Q K^T) V, output scattered through the reference's
// cat/transpose/view permutation directly into Y (bf16 [4096 x 4096]).
__global__ __launch_bounds__(256)
void attn_kernel(const uint16_t* __restrict__ Q, const uint16_t* __restrict__ Kg,
                 const uint16_t* __restrict__ V, uint16_t* __restrict__ Y)
{
    const int bid = blockIdx.x;
    const int hh  = bid & 63;
    const int bb  = bid >> 6;
    const int tid = threadIdx.x;
    const int w   = tid >> 6, lane = tid & 63, g = lane >> 4, l16 = lane & 15;

    __shared__ uint16_t Vt[64 * 64];   // V transposed, XOR-swizzled (8 KB)
    __shared__ uint16_t Pl[64 * 64];   // P bf16, XOR-swizzled (8 KB)

    // ---- stage V transposed: Vt[l][k] = V[k][l], swizzle elem k ^= (l&7)<<3
    {
        const int k  = tid >> 2;
        const int l0 = (tid & 3) * 16;
        const uint16_t* src = V + (size_t)(bb * 64 + k) * 4096 + hh * 64 + l0;
        u16x8 v0 = *reinterpret_cast<const u16x8*>(src);
        u16x8 v1 = *reinterpret_cast<const u16x8*>(src + 8);
#pragma unroll
        for (int i = 0; i < 8; ++i) {
            int l = l0 + i;
            Vt[l * 64 + (k ^ ((l & 7) << 3))] = v0[i];
        }
#pragma unroll
        for (int i = 0; i < 8; ++i) {
            int l = l0 + 8 + i;
            Vt[l * 64 + (k ^ ((l & 7) << 3))] = v1[i];
        }
    }

    // ---- S = Q K^T (rows 16w..16w+16, all 64 cols), direct-global fragments
    f32x4 sa[4] = {};
    {
        const uint16_t* qrow = Q + (size_t)(bb * 64 + w * 16 + l16) * 4096 + hh * 64 + g * 8;
        bf16x8 a0 = *reinterpret_cast<const bf16x8*>(qrow);
        bf16x8 a1 = *reinterpret_cast<const bf16x8*>(qrow + 32);
#pragma unroll
        for (int n = 0; n < 4; ++n) {
            const uint16_t* krow = Kg + (size_t)(bb * 64 + n * 16 + l16) * 4096 + hh * 64 + g * 8;
            bf16x8 b0 = *reinterpret_cast<const bf16x8*>(krow);
            bf16x8 b1 = *reinterpret_cast<const bf16x8*>(krow + 32);
            sa[n] = MFMA16(a0, b0, sa[n]);
            sa[n] = MFMA16(a1, b1, sa[n]);
        }
    }

    // ---- softmax (no 1/sqrt(hd) scale, faithful). Row q = 16w + 4g + j;
    // its 64 values live as regs n=0..3 across the 16-lane group (l16).
    float p[4][4];
#pragma unroll
    for (int j = 0; j < 4; ++j) {
        float mx = fmaxf(fmaxf(sa[0][j], sa[1][j]), fmaxf(sa[2][j], sa[3][j]));
        mx = fmaxf(mx, __shfl_xor(mx, 1));
        mx = fmaxf(mx, __shfl_xor(mx, 2));
        mx = fmaxf(mx, __shfl_xor(mx, 4));
        mx = fmaxf(mx, __shfl_xor(mx, 8));
        float s = 0.f;
#pragma unroll
        for (int n = 0; n < 4; ++n) { p[n][j] = __expf(sa[n][j] - mx); s += p[n][j]; }
        s += __shfl_xor(s, 1);
        s += __shfl_xor(s, 2);
        s += __shfl_xor(s, 4);
        s += __shfl_xor(s, 8);
        float inv = 1.0f / s;
#pragma unroll
        for (int n = 0; n < 4; ++n) p[n][j] *= inv;
    }

    // ---- P -> LDS in A-operand-friendly layout (swizzled)
#pragma unroll
    for (int j = 0; j < 4; ++j) {
        const int q = w * 16 + g * 4 + j;
#pragma unroll
        for (int n = 0; n < 4; ++n) {
            const int kcol = n * 16 + l16;
            Pl[q * 64 + (kcol ^ ((q & 7) << 3))] = f2bf(p[n][j]);
        }
    }
    __syncthreads();   // Vt (all threads) + Pl ready

    // ---- O = P V
    f32x4 oa[4] = {};
    {
        const int qr = w * 16 + l16;
        bf16x8 a0 = *reinterpret_cast<const bf16x8*>(&Pl[qr * 64 + ((g * 8)      ^ ((qr & 7) << 3))]);
        bf16x8 a1 = *reinterpret_cast<const bf16x8*>(&Pl[qr * 64 + ((32 + g * 8) ^ ((qr & 7) << 3))]);
#pragma unroll
        for (int n = 0; n < 4; ++n) {
            const int vr = n * 16 + l16;
            bf16x8 b0 = *reinterpret_cast<const bf16x8*>(&Vt[vr * 64 + ((g * 8)      ^ ((vr & 7) << 3))]);
            bf16x8 b1 = *reinterpret_cast<const bf16x8*>(&Vt[vr * 64 + ((32 + g * 8) ^ ((vr & 7) << 3))]);
            oa[n] = MFMA16(a0, b0, oa[n]);
            oa[n] = MFMA16(a1, b1, oa[n]);
        }
    }

    // ---- permuted store: Ostd[bb,hh,qq,ll] -> Y[b, s, h*64 + l]
#pragma unroll
    for (int n = 0; n < 4; ++n) {
        const int ll = n * 16 + l16;
#pragma unroll
        for (int r = 0; r < 4; ++r) {
            const int qq = w * 16 + g * 4 + r;
            const int b_ = (bb >> 1) + ((ll >= 32) ? 32 : 0);
            const int s_ = ((bb & 1) << 5) + (qq >> 1);
            const int h_ = ((qq & 1) << 5) + (hh >> 1);
            const int l_ = ((hh & 1) << 5) + (ll & 31);
            Y[(size_t)(b_ * 64 + s_) * 4096 + h_ * 64 + l_] = f2bf(oa[n][r]);
        }
    }
}

// ----------------------------------------------------------------------------
extern "C" void kernel_launch(void* const* d_in, const int* in_sizes, int n_in,
                              void* d_out, int out_size, void* d_ws, size_t ws_size,
                              hipStream_t stream)
{
    (void)in_sizes; (void)n_in; (void)out_size; (void)ws_size;

    const float* x  = (const float*)d_in[0];
    const float* Wq = (const float*)d_in[1];
    const float* bq = (const float*)d_in[2];
    const float* Wk = (const float*)d_in[3];
    const float* bk = (const float*)d_in[4];
    const float* Wv = (const float*)d_in[5];
    const float* bv = (const float*)d_in[6];
    const float* Wp = (const float*)d_in[7];
    const float* bp = (const float*)d_in[8];
    float* out = (float*)d_out;

    const size_t NN = 16777216;            // 4096*4096 elements
    uint16_t* xb   = (uint16_t*)d_ws;      // 32 MB, later reused as Y
    uint16_t* wb   = xb + NN;              // 32 MB (sequential weight buffer)
    uint16_t* Qb   = wb + NN;              // 32 MB
    uint16_t* Kb   = Qb + NN;              // 32 MB
    uint16_t* Vb   = Kb + NN;              // 32 MB   (total 160 MB)
    uint16_t* Yb   = xb;

    const int n8 = (int)(NN / 8);
    dim3 cgrid((n8 + 255) / 256), cblk(256);
    dim3 ggrid(256), gblk(512);

    cvt_bf16<<<cgrid, cblk, 0, stream>>>(x, xb, n8);

    cvt_bf16<<<cgrid, cblk, 0, stream>>>(Wq, wb, n8);
    gemm256<1><<<ggrid, gblk, 0, stream>>>(xb, wb, bq, (void*)Qb, 4096, 4096, 4096);

    cvt_bf16<<<cgrid, cblk, 0, stream>>>(Wk, wb, n8);
    gemm256<1><<<ggrid, gblk, 0, stream>>>(xb, wb, bk, (void*)Kb, 4096, 4096, 4096);

    cvt_bf16<<<cgrid, cblk, 0, stream>>>(Wv, wb, n8);
    gemm256<1><<<ggrid, gblk, 0, stream>>>(xb, wb, bv, (void*)Vb, 4096, 4096, 4096);

    attn_kernel<<<dim3(4096), dim3(256), 0, stream>>>(Qb, Kb, Vb, Yb);

    cvt_bf16<<<cgrid, cblk, 0, stream>>>(Wp, wb, n8);
    gemm256<0><<<ggrid, gblk, 0, stream>>>(Yb, wb, bp, (void*)out, 4096, 4096, 4096);
}